// Round 16
// baseline (139.735 us; speedup 1.0000x reference)
//
#include <hip/hip_runtime.h>
#include <math.h>

// B=64, N=27, D=512. EPS=1e-5.
// Identities: (1) uniform-softmax collapse -> all N^2 tensors are broadcasts
// of (B,D) vectors; (2) msg BN stats decompose (per-i/per-j sums + Gram);
// (3) weight-collapse: e0 = g@Wc^T + bc, f0 = g@Wd^T + bcE with
//     Wc = ep@av@fv, Wd = (E1@ep)@av@fv (bf16 MFMA products).
// R16: m1 tile 128x64 -> 128x32 (N-split): grid 512 -> 1024 = 4 blocks/CU
// (was grid-limited at 2). LDS row stride / swizzle / A-side staging are
// UNCHANGED (R14's bank-collapse came from changing row stride; excluded).
// 7 dispatches: dpre, m1, d2(+w2), d3, d4, d8, d9.

#define EPSC 1e-5f

typedef short short8 __attribute__((ext_vector_type(8)));
typedef float f32x4 __attribute__((ext_vector_type(4)));

// ---- ws layout (float offsets) ----
#define YB_OFF   0u          // 1728*2048
#define GF_OFF   3538944u
#define G_OFF    3571712u
#define E0_OFF   3604480u
#define F0_OFF   3637248u
#define EE_OFF   3670016u
#define XN_OFF   3702784u    // 884736
#define RE1_OFF  4587520u    // 512
#define PAC_OFF  4588032u    // 768
#define ST_OFF   4588800u    // 256
#define XB_OFF   4589056u    // bf16 X
#define WB_OFF   5031424u    // bf16 A1,B1,V1,U1
#define AVB_OFF  5555712u    // bf16 av (straight)
#define EPB_OFF  5686784u    // bf16 ep (straight)
#define E1B_OFF  5817856u    // bf16 E1 (straight)
#define FVT_OFF  5948928u    // bf16 fv^T
#define EPT_OFF  6080000u    // bf16 ep^T
#define T1T_OFF  6211072u    // bf16 (av@fv)^T
#define WEB_OFF  6342144u    // bf16 E1@ep
#define WC_OFF   6473216u    // fp32 ep@av@fv
#define WD_OFF   6735360u    // fp32 E1@ep@av@fv
#define BC0_OFF  6997504u
#define BC_OFF   6998016u
#define BCE_OFF  6998528u
// ST: [0..27) Sa, [27..54) Sa2, [54..81) Sc, [81..108) Sc2,
//     [108..135) sae(at), [135..162) sce(at), [162..164) se,se2(at),
//     [164..166) s_acc(at), [166..220) pbn_acc(at)

__device__ __forceinline__ unsigned short f2bf(float f) {
    unsigned int u = __float_as_uint(f);
    return (unsigned short)((u + 0x7FFFu + ((u >> 16) & 1u)) >> 16);
}

__device__ __forceinline__ float wred64(float v) {
#pragma unroll
    for (int o = 32; o; o >>= 1) v += __shfl_down(v, o, 64);
    return v;
}

// ============ job: coalesced matvec / rowsum, 64 outputs per block ============
__device__ void mv_cw(const float* __restrict__ W, const float* __restrict__ vin,
                      const float* __restrict__ badd, float* __restrict__ vout,
                      int jb, int t, char* sbuf) {
    float* vs = (float*)sbuf;
    if (t < 128) {
        float4 one = make_float4(1.f, 1.f, 1.f, 1.f);
        ((float4*)vs)[t] = vin ? ((const float4*)vin)[t] : one;
    }
    __syncthreads();
    int w = t >> 6, lane = t & 63;
    for (int o = 0; o < 16; o++) {
        int d = jb * 64 + w * 16 + o;
        const float* row = W + (size_t)d * 512;
        float4 v1 = *(const float4*)(row + lane * 4);
        float4 v2 = *(const float4*)(row + 256 + lane * 4);
        const float* va = vs + lane * 4;
        const float* vb = vs + 256 + lane * 4;
        float p = v1.x * va[0] + v1.y * va[1] + v1.z * va[2] + v1.w * va[3]
                + v2.x * vb[0] + v2.y * vb[1] + v2.z * vb[2] + v2.w * vb[3];
        p = wred64(p);
        if (lane == 0) vout[d] = p + (badd ? badd[d] : 0.f);
    }
}

// ============ dpre: gf + rE1 + zero + all bf16 conversions + bc0 ============
__global__ __launch_bounds__(256) void dpre_k(const float* __restrict__ x,
        const float* __restrict__ E1, const float* __restrict__ A1,
        const float* __restrict__ B1, const float* __restrict__ V1,
        const float* __restrict__ U1, const float* __restrict__ fv_w,
        const float* __restrict__ av_w, const float* __restrict__ ep_w,
        const float* __restrict__ fv_b, const float* __restrict__ av_b,
        float* __restrict__ ws) {
    __shared__ __align__(16) char sbuf[17408];
    int blk = blockIdx.x, t = threadIdx.x;
    if (blk < 16) {
        float* gf = ws + GF_OFF;
        for (int p = 0; p < 8; p++) {
            int q = blk * 2048 + p * 256 + t;
            int b = q >> 9, d = q & 511;
            const float* pp = x + (size_t)b * 13824 + d;
            float s = 0.f;
#pragma unroll
            for (int n = 0; n < 27; n++) s += pp[n << 9];
            gf[q] = s * (1.0f / 27.0f);
        }
    } else if (blk < 24) {
        mv_cw(E1, nullptr, nullptr, ws + RE1_OFF, blk - 16, t, sbuf);
    } else if (blk < 25) {
        float* pac = ws + PAC_OFF;
        float* ST = ws + ST_OFF;
        for (int q = t; q < 729; q += 256) pac[q] = 0.f;
        if (t < 112) ST[108 + t] = 0.f;
    } else if (blk < 52) {
        int jb = blk - 25;   // X -> bf16
        unsigned short* xb = (unsigned short*)(ws + XB_OFF);
        size_t base = (size_t)jb * 32768;
#pragma unroll
        for (int it = 0; it < 16; it++) {
            size_t e8 = base + it * 2048 + t * 8;
            float4 a = *(const float4*)(x + e8);
            float4 b = *(const float4*)(x + e8 + 4);
            uint4 pk;
            pk.x = f2bf(a.x) | ((unsigned)f2bf(a.y) << 16);
            pk.y = f2bf(a.z) | ((unsigned)f2bf(a.w) << 16);
            pk.z = f2bf(b.x) | ((unsigned)f2bf(b.y) << 16);
            pk.w = f2bf(b.z) | ((unsigned)f2bf(b.w) << 16);
            *(uint4*)(xb + e8) = pk;
        }
    } else if (blk < 84) {
        int jb = blk - 52;   // A1/B1/V1/U1 -> bf16
        const float* Wl[4] = {A1, B1, V1, U1};
        const float* src = Wl[jb >> 3] + (size_t)(jb & 7) * 32768;
        unsigned short* wb = (unsigned short*)(ws + WB_OFF) + (size_t)jb * 32768;
#pragma unroll
        for (int it = 0; it < 16; it++) {
            size_t e8 = (size_t)it * 2048 + t * 8;
            float4 a = *(const float4*)(src + e8);
            float4 b = *(const float4*)(src + e8 + 4);
            uint4 pk;
            pk.x = f2bf(a.x) | ((unsigned)f2bf(a.y) << 16);
            pk.y = f2bf(a.z) | ((unsigned)f2bf(a.w) << 16);
            pk.z = f2bf(b.x) | ((unsigned)f2bf(b.y) << 16);
            pk.w = f2bf(b.z) | ((unsigned)f2bf(b.w) << 16);
            *(uint4*)(wb + e8) = pk;
        }
    } else if (blk < 92) {
        mv_cw(av_w, fv_b, av_b, ws + BC0_OFF, blk - 84, t, sbuf);  // bc0
    } else if (blk < 116) {
        int jb = blk - 92;   // straight bf16: av, ep, E1 (8 blocks each)
        const float* Sl[3] = {av_w, ep_w, E1};
        unsigned dofs[3] = {AVB_OFF, EPB_OFF, E1B_OFF};
        const float* src = Sl[jb >> 3] + (size_t)(jb & 7) * 32768;
        unsigned short* wb = (unsigned short*)(ws + dofs[jb >> 3]) + (size_t)(jb & 7) * 32768;
#pragma unroll
        for (int it = 0; it < 16; it++) {
            size_t e8 = (size_t)it * 2048 + t * 8;
            float4 a = *(const float4*)(src + e8);
            float4 b = *(const float4*)(src + e8 + 4);
            uint4 pk;
            pk.x = f2bf(a.x) | ((unsigned)f2bf(a.y) << 16);
            pk.y = f2bf(a.z) | ((unsigned)f2bf(a.w) << 16);
            pk.z = f2bf(b.x) | ((unsigned)f2bf(b.y) << 16);
            pk.w = f2bf(b.z) | ((unsigned)f2bf(b.w) << 16);
            *(uint4*)(wb + e8) = pk;
        }
    } else {
        // transposed bf16 conv: fv^T (blk 116..179), ep^T (180..243)
        int jb = blk - 116;
        const float* src = (jb < 64) ? fv_w : ep_w;
        unsigned short* dst = (unsigned short*)(ws + ((jb < 64) ? FVT_OFF : EPT_OFF));
        int tile = jb & 63;
        int tr = (tile >> 3) * 64, tc = (tile & 7) * 64;  // src rows (k), cols (j)
        float* T = (float*)sbuf;                          // [64][67]
        {
            int row = t >> 2, cs = t & 3;
#pragma unroll
            for (int q = 0; q < 4; q++) {
                int col = cs * 16 + q * 4;
                float4 v = *(const float4*)(src + (size_t)(tr + row) * 512 + tc + col);
                T[row * 67 + col] = v.x; T[row * 67 + col + 1] = v.y;
                T[row * 67 + col + 2] = v.z; T[row * 67 + col + 3] = v.w;
            }
        }
        __syncthreads();
        {
            int jrow = t >> 2, seg = t & 3;
            unsigned u[8];
#pragma unroll
            for (int q = 0; q < 8; q++) {
                float lo = T[(seg * 16 + 2 * q) * 67 + jrow];
                float hi = T[(seg * 16 + 2 * q + 1) * 67 + jrow];
                u[q] = f2bf(lo) | ((unsigned)f2bf(hi) << 16);
            }
            unsigned short* op = dst + (size_t)(tc + jrow) * 512 + tr + seg * 16;
            *(uint4*)op = make_uint4(u[0], u[1], u[2], u[3]);
            *(uint4*)(op + 8) = make_uint4(u[4], u[5], u[6], u[7]);
        }
    }
}

// ============ M1: unified MFMA dispatch (BK=32, BM=128, BN=32) ============
// Yb (896 blocks) + w1 jobs (128 blocks); 1024 total = 4 blocks/CU.
__global__ __launch_bounds__(256) void m1_k(const unsigned short* __restrict__ Xb,
        const unsigned short* __restrict__ Wb,
        const unsigned short* __restrict__ fvT, const unsigned short* __restrict__ avB,
        const unsigned short* __restrict__ e1B, const unsigned short* __restrict__ epT,
        float* __restrict__ Y, unsigned short* __restrict__ T1t,
        unsigned short* __restrict__ WeB) {
    __shared__ __align__(16) unsigned short As[128 * 32];   // 8 KB (unchanged)
    __shared__ __align__(16) unsigned short Bs[32 * 32];    // 2 KB
    int blk = blockIdx.x, t = threadIdx.x;
    const unsigned short* abase;
    const unsigned short* bbase;
    int rb0, mrows, col0;
    size_t ostride;
    float* outf = nullptr;
    unsigned short* outh = nullptr;
    if (blk < 896) {
        int bx = blk % 14, by = blk / 14;          // by 0..63 (32-col tiles)
        rb0 = bx * 128; mrows = 1728;
        abase = Xb;
        bbase = Wb + ((size_t)(by >> 4) * 512 + (size_t)(by & 15) * 32) * 512;
        outf = Y; col0 = by * 32; ostride = 2048;
    } else {
        int j = blk - 896;          // 0..127
        int sel = j >> 6, loc = j & 63;
        int bx = loc & 3, by = loc >> 2;           // by 0..15
        rb0 = bx * 128; mrows = 512;
        abase = sel ? e1B : fvT;
        bbase = (sel ? epT : avB) + (size_t)(by * 32) * 512;
        outh = sel ? WeB : T1t; col0 = by * 32; ostride = 512;
    }
    // staging roles: A (t<128, unchanged map) ; B (t in [128,160), 32 rows)
    bool isA = t < 128, isB = (t >= 128 && t < 160);
    int sr;
    if (isA) sr = (t & 64) + (((t & 1) << 5) | ((t & 63) >> 1));
    else { int u = (t - 128) & 31; sr = ((u & 1) << 4) | (u >> 1); }
    const unsigned short* src = nullptr;
    bool valid = false;
    if (isA) { int gr = rb0 + sr; valid = gr < mrows; src = abase + (size_t)gr * 512; }
    else if (isB) { valid = true; src = bbase + (size_t)sr * 512; }
    unsigned short* dst = (isA ? As : Bs) + sr * 32;
    int rsh = (sr >> 1) & 3;
    int wave = t >> 6, l = t & 63;
    int wr = (wave >> 1) * 64, wc = (wave & 1) * 16;
    int lr = l & 15, g = l >> 4;
    f32x4 acc[4] = {};
    uint4 v[4];
    uint4 z4 = make_uint4(0u, 0u, 0u, 0u);
    if (isA || isB) {
        const uint4* sp = (const uint4*)src;
#pragma unroll
        for (int i = 0; i < 4; i++) v[i] = valid ? sp[i] : z4;
    }
    for (int step = 0; step < 16; step++) {
        __syncthreads();
        if (isA || isB) {
#pragma unroll
            for (int s = 0; s < 4; s++)
                *(uint4*)(dst + (((s + rsh) & 3) << 3)) = v[s];
            if (step < 15) {
                const uint4* sp = (const uint4*)(src + (step + 1) * 32);
#pragma unroll
                for (int i = 0; i < 4; i++) v[i] = valid ? sp[i] : z4;
            }
        }
        __syncthreads();
        short8 af[4], bf;
#pragma unroll
        for (int m = 0; m < 4; m++) {
            int r = wr + m * 16 + lr;
            af[m] = *(const short8*)(As + r * 32 + (((g + (r >> 1)) & 3) << 3));
        }
        {
            int r = wc + lr;
            bf = *(const short8*)(Bs + r * 32 + (((g + (r >> 1)) & 3) << 3));
        }
#pragma unroll
        for (int m = 0; m < 4; m++)
            acc[m] = __builtin_amdgcn_mfma_f32_16x16x32_bf16(af[m], bf, acc[m], 0, 0, 0);
    }
#pragma unroll
    for (int m = 0; m < 4; m++) {
        int row0 = rb0 + wr + m * 16 + g * 4;
#pragma unroll
        for (int reg = 0; reg < 4; reg++) {
            int row = row0 + reg;
            if (row < mrows) {
                int col = col0 + wc + lr;
                if (outf) outf[(size_t)row * ostride + col] = acc[m][reg];
                else      outh[(size_t)row * ostride + col] = f2bf(acc[m][reg]);
            }
        }
    }
}

// ============ MFMA core for w2 jobs (proven BK=32, 128x64 structure), M=512 ============
__device__ __forceinline__ void wgemm_core(const unsigned short* __restrict__ A,
        const unsigned short* __restrict__ B, float* __restrict__ Out,
        int bx, int by, int t, unsigned short* As, unsigned short* Bs) {
    int rb0 = bx * 128, n0 = by * 64;
    bool isA = t < 128, isB = (t >= 128 && t < 192);
    int sr;
    if (isA) sr = (t & 64) + (((t & 1) << 5) | ((t & 63) >> 1));
    else { int u = (t - 128) & 63; sr = ((u & 1) << 5) | (u >> 1); }
    const unsigned short* src = isA ? A + (size_t)(rb0 + sr) * 512
                                    : B + (size_t)(n0 + sr) * 512;
    unsigned short* dst = (isA ? As : Bs) + sr * 32;
    int rsh = (sr >> 1) & 3;
    int wave = t >> 6, l = t & 63;
    int wr = (wave >> 1) * 64, wc = (wave & 1) * 32;
    int lr = l & 15, g = l >> 4;
    f32x4 acc[4][2] = {};
    uint4 v[4];
    if (isA || isB) {
        const uint4* sp = (const uint4*)src;
#pragma unroll
        for (int i = 0; i < 4; i++) v[i] = sp[i];
    }
    for (int step = 0; step < 16; step++) {
        __syncthreads();
        if (isA || isB) {
#pragma unroll
            for (int s = 0; s < 4; s++)
                *(uint4*)(dst + (((s + rsh) & 3) << 3)) = v[s];
            if (step < 15) {
                const uint4* sp = (const uint4*)(src + (step + 1) * 32);
#pragma unroll
                for (int i = 0; i < 4; i++) v[i] = sp[i];
            }
        }
        __syncthreads();
        short8 af[4], bf[2];
#pragma unroll
        for (int m = 0; m < 4; m++) {
            int r = wr + m * 16 + lr;
            af[m] = *(const short8*)(As + r * 32 + (((g + (r >> 1)) & 3) << 3));
        }
#pragma unroll
        for (int n = 0; n < 2; n++) {
            int r = wc + n * 16 + lr;
            bf[n] = *(const short8*)(Bs + r * 32 + (((g + (r >> 1)) & 3) << 3));
        }
#pragma unroll
        for (int m = 0; m < 4; m++)
#pragma unroll
            for (int n = 0; n < 2; n++)
                acc[m][n] = __builtin_amdgcn_mfma_f32_16x16x32_bf16(af[m], bf[n], acc[m][n], 0, 0, 0);
    }
#pragma unroll
    for (int m = 0; m < 4; m++) {
        int row0 = rb0 + wr + m * 16 + g * 4;
#pragma unroll
        for (int reg = 0; reg < 4; reg++) {
            int row = row0 + reg;
#pragma unroll
            for (int n = 0; n < 2; n++)
                Out[(size_t)row * 512 + n0 + wc + n * 16 + lr] = acc[m][n][reg];
        }
    }
}

// ============ job: Out[64x512]=A@W^T, 4 d/block; As[64][132] direct layout ============
__device__ void dense4x_job(const float* __restrict__ A, const float* __restrict__ W,
                            const float* __restrict__ bias, float* __restrict__ Out,
                            int jb, int t, char* sbuf, int mode, float* __restrict__ ST) {
    float* As = (float*)sbuf;          // [64][132]
    float* Ws = As + 64 * 132;         // [4][132]
    float* red = Ws + 4 * 132;         // [8]
    int d0 = jb * 4;
    int b = t & 63, dg = t >> 6;
    int d = d0 + dg;
    float a0 = 0.f, a1 = 0.f, a2 = 0.f, a3 = 0.f;
    for (int c = 0; c < 4; c++) {
        int k0 = c * 128;
#pragma unroll
        for (int r = 0; r < 8; r++) {
            int p = t + r * 256;
            int row = p >> 5, c4 = p & 31;
            *(float4*)(As + row * 132 + c4 * 4) =
                *(const float4*)(A + (size_t)row * 512 + k0 + c4 * 4);
        }
        if (t < 128) {
            int drow = t >> 5, c4 = t & 31;
            *(float4*)(Ws + drow * 132 + c4 * 4) =
                *(const float4*)(W + (size_t)(d0 + drow) * 512 + k0 + c4 * 4);
        }
        __syncthreads();
        const float4* ap = (const float4*)(As + b * 132);
        const float4* wp = (const float4*)(Ws + dg * 132);
#pragma unroll 8
        for (int kq = 0; kq < 32; kq += 4) {
            float4 x0 = ap[kq], w0 = wp[kq];
            float4 x1 = ap[kq + 1], w1 = wp[kq + 1];
            float4 x2 = ap[kq + 2], w2 = wp[kq + 2];
            float4 x3 = ap[kq + 3], w3 = wp[kq + 3];
            a0 = fmaf(x0.x, w0.x, fmaf(x0.y, w0.y, fmaf(x0.z, w0.z, fmaf(x0.w, w0.w, a0))));
            a1 = fmaf(x1.x, w1.x, fmaf(x1.y, w1.y, fmaf(x1.z, w1.z, fmaf(x1.w, w1.w, a1))));
            a2 = fmaf(x2.x, w2.x, fmaf(x2.y, w2.y, fmaf(x2.z, w2.z, fmaf(x2.w, w2.w, a2))));
            a3 = fmaf(x3.x, w3.x, fmaf(x3.y, w3.y, fmaf(x3.z, w3.z, fmaf(x3.w, w3.w, a3))));
        }
        __syncthreads();
    }
    float val = (a0 + a1) + (a2 + a3) + (bias ? bias[d] : 0.f);
    if (mode == 1) {
        float sv = __shfl(wred64(val), 0, 64);
        float sv2 = __shfl(wred64(val * val), 0, 64);
        float mm = sv * (1.f / 64.f);
        float var = sv2 * (1.f / 64.f) - mm * mm;
        val = fmaxf((val - mm) / sqrtf(var + EPSC), 0.f);
    }
    Out[b * 512 + d] = val;
    if (mode == 2) {
        float s = wred64(val), s2 = wred64(val * val);
        if ((t & 63) == 0) { red[dg * 2] = s; red[dg * 2 + 1] = s2; }
        __syncthreads();
        if (t == 0) {
            atomicAdd(ST + 164, red[0] + red[2] + red[4] + red[6]);
            atomicAdd(ST + 165, red[1] + red[3] + red[5] + red[7]);
        }
    }
}

// ============ job: Gram partials (atomic) ============
__device__ void gram_job(const float* __restrict__ Yb, float* __restrict__ pac,
                         int b, int t, char* sbuf) {
    float* As = (float*)sbuf;        // [27][132]
    float* Cs = As + 27 * 132;
    float a0 = 0, a1 = 0, a2 = 0;
    int i = t / 9, j0 = (t % 9) * 3;
    for (int dc = 0; dc < 4; dc++) {
        const float* base = Yb + (size_t)b * 27 * 2048 + dc * 128;
#pragma unroll
        for (int r = 0; r < 4; r++) {
            int id = t + r * 256;
            if (id < 864) {
                int row = id >> 5, c4 = (id & 31) << 2;
                *(float4*)&As[row * 132 + c4] = *(const float4*)(base + (size_t)row * 2048 + c4);
                *(float4*)&Cs[row * 132 + c4] = *(const float4*)(base + (size_t)row * 2048 + 512 + c4);
            }
        }
        __syncthreads();
        if (t < 243) {
#pragma unroll
            for (int k = 0; k < 128; k += 4) {
                float4 av = *(const float4*)&As[i * 132 + k];
                float4 c0 = *(const float4*)&Cs[j0 * 132 + k];
                float4 c1 = *(const float4*)&Cs[(j0 + 1) * 132 + k];
                float4 c2 = *(const float4*)&Cs[(j0 + 2) * 132 + k];
                a0 += av.x * c0.x + av.y * c0.y + av.z * c0.z + av.w * c0.w;
                a1 += av.x * c1.x + av.y * c1.y + av.z * c1.z + av.w * c1.w;
                a2 += av.x * c2.x + av.y * c2.y + av.z * c2.z + av.w * c2.w;
            }
        }
        __syncthreads();
    }
    if (t < 243) {
        atomicAdd(pac + i * 27 + j0, a0);
        atomicAdd(pac + i * 27 + j0 + 1, a1);
        atomicAdd(pac + i * 27 + j0 + 2, a2);
    }
}

// ============ job: per-i a/c sums — float4 + unroll ============
__device__ void acsum_job(const float* __restrict__ Yb, float* __restrict__ ST,
                          int ia, int t, char* sbuf) {
    int i = ia < 27 ? ia : ia - 27;
    int off = ia < 27 ? 0 : 512;
    float s = 0, s2 = 0;
#pragma unroll 8
    for (int q4 = t; q4 < 8192; q4 += 256) {
        int b = q4 >> 7, d4 = (q4 & 127) << 2;
        float4 v = *(const float4*)(Yb + (size_t)(b * 27 + i) * 2048 + off + d4);
        s += (v.x + v.y) + (v.z + v.w);
        s2 += v.x * v.x + v.y * v.y + v.z * v.z + v.w * v.w;
    }
    s = wred64(s); s2 = wred64(s2);
    float* p = (float*)sbuf;
    int wv_ = t >> 6;
    if ((t & 63) == 0) { p[wv_ * 2] = s; p[wv_ * 2 + 1] = s2; }
    __syncthreads();
    if (t == 0) {
        float S = p[0] + p[2] + p[4] + p[6];
        float S2 = p[1] + p[3] + p[5] + p[7];
        if (ia < 27) { ST[ia] = S; ST[27 + ia] = S2; }
        else { ST[54 + (ia - 27)] = S; ST[81 + (ia - 27)] = S2; }
    }
}

// ============ D2: w2 (64) + g (128) + gram (64) + acsum (54) + bc (8) ============
__global__ __launch_bounds__(256) void d2_k(const float* __restrict__ gl_w,
        const float* __restrict__ gl_b, const float* __restrict__ ep_w,
        const float* __restrict__ ep_b, float* __restrict__ ws) {
    __shared__ __align__(16) char sbuf[36032];
    int blk = blockIdx.x, t = threadIdx.x;
    if (blk < 64) {
        unsigned short* As = (unsigned short*)sbuf;
        unsigned short* Bs = As + 128 * 32;
        int sel = blk >> 5, loc = blk & 31;
        const unsigned short* epB = (const unsigned short*)(ws + EPB_OFF);
        const unsigned short* WeB = (const unsigned short*)(ws + WEB_OFF);
        const unsigned short* T1t = (const unsigned short*)(ws + T1T_OFF);
        wgemm_core(sel ? WeB : epB, T1t, sel ? (ws + WD_OFF) : (ws + WC_OFF),
                   loc & 3, loc >> 2, t, As, Bs);
    } else if (blk < 192) {
        dense4x_job(ws + GF_OFF, gl_w, gl_b, ws + G_OFF, blk - 64, t, sbuf, 1, nullptr);
    } else if (blk < 256) {
        gram_job(ws + YB_OFF, ws + PAC_OFF, blk - 192, t, sbuf);
    } else if (blk < 310) {
        acsum_job(ws + YB_OFF, ws + ST_OFF, blk - 256, t, sbuf);
    } else {
        mv_cw(ep_w, ws + BC0_OFF, ep_b, ws + BC_OFF, blk - 310, t, sbuf);
    }
}

// ============ D3: e0 = g@Wc^T+bc (stats) + f0 = g@Wd^T + bcE matvec ============
__global__ __launch_bounds__(256) void d3_k(const float* __restrict__ E1,
        float* __restrict__ ws) {
    __shared__ __align__(16) char sbuf[36032];
    int blk = blockIdx.x, t = threadIdx.x;
    if (blk < 128) {
        dense4x_job(ws + G_OFF, ws + WC_OFF, ws + BC_OFF, ws + E0_OFF,
                    blk, t, sbuf, 2, ws + ST_OFF);
    } else if (blk < 256) {
        dense4x_job(ws + G_OFF, ws + WD_OFF, nullptr, ws + F0_OFF,
                    blk - 128, t, sbuf, 0, nullptr);
    } else {
        mv_cw(E1, ws + BC_OFF, nullptr, ws + BCE_OFF, blk - 256, t, sbuf);
    }
}

// ============ D4: eE + se/se2 (8) + sae/sce (216) — float4 ============
__global__ __launch_bounds__(256) void d4_k(float* __restrict__ ws) {
    __shared__ __align__(16) char sbuf[64];
    int blk = blockIdx.x, t = threadIdx.x;
    const float* Yb = ws + YB_OFF;
    const float* f0 = ws + F0_OFF;
    const float* bcE = ws + BCE_OFF;
    const float* rE1 = ws + RE1_OFF;
    float* ST = ws + ST_OFF;
    float m = ST[164] * (1.f / 32768.f);
    float var = ST[165] * (1.f / 32768.f) - m * m;
    float rs = 1.f / sqrtf(var + EPSC);
    float* p = (float*)sbuf;
    int wv_ = t >> 6;
    if (blk < 8) {
        float se = 0.f, se2 = 0.f;
#pragma unroll
        for (int r = 0; r < 4; r++) {
            int q4 = blk * 1024 + r * 256 + t;
            int d4 = (q4 & 127) << 2;
            float4 f = *(const float4*)(f0 + q4 * 4);
            float4 bc4 = *(const float4*)(bcE + d4);
            float4 re4 = *(const float4*)(rE1 + d4);
            float4 e;
            e.x = rs * (f.x + bc4.x - m * re4.x);
            e.y = rs * (f.y + bc4.y - m * re4.y);
            e.z = rs * (f.z + bc4.z - m * re4.z);
            e.w = rs * (f.w + bc4.w - m * re4.w);
            *(float4*)(ws + EE_OFF + q4 * 4) = e;
            se += (e.x + e.y) + (e.z + e.w);
            se2 += e.x * e.x + e.y * e.y + e.z * e.z + e.w * e.w;
        }
        se = wred64(se); se2 = wred64(se2);
        if ((t & 63) == 0) { p[wv_ * 2] = se; p[wv_ * 2 + 1] = se2; }
        __syncthreads();
        if (t == 0) {
            atomicAdd(ST + 162, p[0] + p[2] + p[4] + p[6]);
            atomicAdd(ST + 163, p[1] + p[3] + p[5] + p[7]);
        }
    } else {
        int blk2 = blk - 8;
        int i = blk2 % 27, bg = blk2 / 27;
        float sae = 0.f, sce = 0.f;
#pragma unroll
        for (int r = 0; r < 4; r++) {
            int q4 = r * 256 + t;               // 0..1023 over 8 b x 128 f4
            int bb = bg * 8 + (q4 >> 7);
            int d4 = (q4 & 127) << 2;
            float4 f = *(const float4*)(f0 + bb * 512 + d4);
            float4 bc4 = *(const float4*)(bcE + d4);
            float4 re4 = *(const float4*)(rE1 + d4);
            float4 e;
            e.x = rs * (f.x + bc4.x - m * re4.x);
            e.y = rs * (f.y + bc4.y - m * re4.y);
            e.z = rs * (f.z + bc4.z - m * re4.z);
            e.w = rs * (f.w + bc4.w - m * re4.w);
            size_t base = (size_t)(bb * 27 + i) * 2048 + d4;
            float4 av = *(const float4*)(Yb + base);
            float4 cv = *(const float4*)(Yb + base + 512);
            sae += av.x * e.x + av.y * e.y + av.z * e.z + av.w * e.w;
            sce += cv.x * e.x + cv.y * e.y + cv.z * e.z + cv.w * e.w;
        }
        sae = wred64(sae); sce = wred64(sce);
        if ((t & 63) == 0) { p[wv_ * 2] = sae; p[wv_ * 2 + 1] = sce; }
        __syncthreads();
        if (t == 0) {
            atomicAdd(ST + 108 + i, p[0] + p[2] + p[4] + p[6]);
            atomicAdd(ST + 135 + i, p[1] + p[3] + p[5] + p[7]);
        }
    }
}

// ============ D8: fuse gate/softmax/aggregate (512 blocks, i-split) ============
__global__ __launch_bounds__(256) void d8_k(float* __restrict__ ws) {
    __shared__ __align__(16) char sbuf[5888];
    int blk = blockIdx.x, t = threadIdx.x;
    const float* Yb = ws + YB_OFF;
    const float* eE = ws + EE_OFF;
    const float* e0 = ws + E0_OFF;
    const float* pac = ws + PAC_OFF;
    float* ST = ws + ST_OFF;
    float* xn = ws + XN_OFF;
    float* pbn_acc = ST + 166;
    float* rstL = (float*)sbuf;      // 736
    float* pmsL = rstL + 736;
    int b = blk >> 3, r3 = blk & 7;
    int ds4 = (r3 >> 1) * 128, ih = r3 & 1;
    int i0 = ih ? 14 : 0, i1 = ih ? 27 : 14;
    float Se = ST[162], Se2 = ST[163];
    const float inv = 1.f / 32768.f;
    float mE = ST[164] * inv;
    float varE = ST[165] * inv - mE * mE;
    float rsE = 1.f / sqrtf(varE + EPSC);
    for (int id = i0 * 27 + t; id < i1 * 27; id += 256) {
        int i = id / 27, j = id - i * 27;
        float m = (ST[i] + ST[54 + j] + Se) * inv;
        float S2 = ST[27 + i] + ST[81 + j] + Se2 + 2.f * (pac[id] + ST[108 + i] + ST[135 + j]);
        float var = S2 * inv - m * m;
        float rst = 1.f / sqrtf(var + EPSC);
        rstL[id] = rst; pmsL[id] = -m * rst;
    }
    __syncthreads();
    int j = t & 127, sub = t >> 7;
    float ev = eE[b * 512 + ds4 + j];
    float env = (e0[b * 512 + ds4 + j] - mE) * rsE;
    float cr[27], ur[27];
#pragma unroll
    for (int jj = 0; jj < 27; ++jj) {
        size_t rb = (size_t)(b * 27 + jj) * 2048 + ds4 + j;
        cr[jj] = Yb[rb + 512];
        ur[jj] = Yb[rb + 1024];
    }
    const float L2E = 1.4426950408889634f;
    for (int i = i0 + sub; i < i1; i += 2) {
        size_t rb = (size_t)(b * 27 + i) * 2048 + ds4 + j;
        float t1 = Yb[rb] + ev;
        const float* prst = rstL + i * 27;
        const float* ppms = pmsL + i * 27;
        float num = 0.f, den = 0.f;
#pragma unroll
        for (int jj = 0; jj < 27; ++jj) {
            float bn = fmaf(t1 + cr[jj], prst[jj], ppms[jj]);
            float r = fmaxf(bn, 0.f);
            float z = env + r;
            float tt = __builtin_amdgcn_exp2f(z * -L2E);
            float sg = __builtin_amdgcn_rcpf(1.f + tt);
            float w2 = __builtin_amdgcn_exp2f(sg * L2E);
            den += w2;
            num = fmaf(w2, ur[jj], num);
        }
        xn[(size_t)b * 13824 + i * 512 + ds4 + j] =
            Yb[rb + 1536] + num * __builtin_amdgcn_rcpf(den) * (1.f / 27.f);
    }
    __syncthreads();
    if (t >= i0 && t < i1) {
        float s = 0, s2 = 0;
        const float4* xp = (const float4*)(xn + (size_t)b * 13824 + t * 512 + ds4);
#pragma unroll 8
        for (int q = 0; q < 32; q++) {
            float4 v = xp[q];
            s += (v.x + v.y) + (v.z + v.w);
            s2 += v.x * v.x + v.y * v.y + v.z * v.z + v.w * v.w;
        }
        atomicAdd(pbn_acc + t * 2, s);
        atomicAdd(pbn_acc + t * 2 + 1, s2);
    }
}

// ============ D9: per-n BN + residual relu ============
__global__ __launch_bounds__(256) void d9_k(const float* __restrict__ x,
        float* __restrict__ ws, float* __restrict__ out) {
    __shared__ __align__(16) char sbuf[256];
    int blk = blockIdx.x, t = threadIdx.x;
    const float* xn = ws + XN_OFF;
    const float* pbn_acc = ws + ST_OFF + 166;
    float* m2L = (float*)sbuf;
    float* rs2L = m2L + 32;
    if (t < 27) {
        float S = pbn_acc[t * 2], S2 = pbn_acc[t * 2 + 1];
        float m = S * (1.f / 32768.f);
        float var = S2 * (1.f / 32768.f) - m * m;
        m2L[t] = m; rs2L[t] = 1.f / sqrtf(var + EPSC);
    }
    __syncthreads();
    int b = blk >> 2, ds4 = (blk & 3) * 128;
    int j = t & 127, nh = t >> 7;
    int n0 = nh * 14, n1 = nh ? 27 : 14;
#pragma unroll 4
    for (int n = n0; n < n1; ++n) {
        size_t xi = (size_t)b * 13824 + n * 512 + ds4 + j;
        out[xi] = fmaxf(fmaf(xn[xi] - m2L[n], rs2L[n], x[xi]), 0.f);
    }
}

extern "C" void kernel_launch(void* const* d_in, const int* in_sizes, int n_in,
                              void* d_out, int out_size, void* d_ws, size_t ws_size,
                              hipStream_t stream) {
    const float* x    = (const float*)d_in[0];
    const float* gl_w = (const float*)d_in[1];
    const float* gl_b = (const float*)d_in[2];
    const float* fv_w = (const float*)d_in[7];
    const float* fv_b = (const float*)d_in[8];
    const float* av_w = (const float*)d_in[13];
    const float* av_b = (const float*)d_in[14];
    const float* ep_w = (const float*)d_in[15];
    const float* ep_b = (const float*)d_in[16];
    const float* U1   = (const float*)d_in[17];
    const float* V1   = (const float*)d_in[18];
    const float* A1   = (const float*)d_in[19];
    const float* B1   = (const float*)d_in[20];
    const float* E1   = (const float*)d_in[21];
    float* out = (float*)d_out;
    float* ws = (float*)d_ws;

    dpre_k<<<244, 256, 0, stream>>>(x, E1, A1, B1, V1, U1, fv_w, av_w, ep_w,
                                    fv_b, av_b, ws);
    m1_k<<<1024, 256, 0, stream>>>((const unsigned short*)(ws + XB_OFF),
                                   (const unsigned short*)(ws + WB_OFF),
                                   (const unsigned short*)(ws + FVT_OFF),
                                   (const unsigned short*)(ws + AVB_OFF),
                                   (const unsigned short*)(ws + E1B_OFF),
                                   (const unsigned short*)(ws + EPT_OFF),
                                   ws + YB_OFF,
                                   (unsigned short*)(ws + T1T_OFF),
                                   (unsigned short*)(ws + WEB_OFF));
    d2_k<<<318, 256, 0, stream>>>(gl_w, gl_b, ep_w, ep_b, ws);
    d3_k<<<264, 256, 0, stream>>>(E1, ws);
    d4_k<<<224, 256, 0, stream>>>(ws);
    d8_k<<<512, 256, 0, stream>>>(ws);
    d9_k<<<256, 256, 0, stream>>>(x, ws, out);
}

// Round 17
// 120.387 us; speedup vs baseline: 1.1607x; 1.1607x over previous
//
#include <hip/hip_runtime.h>
#include <math.h>

// B=64, N=27, D=512. EPS=1e-5.
// Identities: (1) uniform-softmax collapse -> all N^2 tensors are broadcasts
// of (B,D) vectors; (2) msg BN stats decompose (per-i/per-j sums + Gram);
// (3) weight-collapse: e0 = g@Wc^T + bc, f0 = g@Wd^T + bcE with
//     Wc = ep@av@fv, Wd = (E1@ep)@av@fv (bf16 MFMA products).
// R17: revert to R15 (best verified config, 120.4/120.7us). R16's 128x32
// tile caused 4x write amplification (59MB WRITE_SIZE) + 1.3M bank
// conflicts; R14's BK=64 caused bank collapse. The 128x64/BK=32 geometry
// is the proven optimum of this structure.
// 7 dispatches: dpre, m1, d2(+w2), d3, d4, d8, d9.

#define EPSC 1e-5f

typedef short short8 __attribute__((ext_vector_type(8)));
typedef float f32x4 __attribute__((ext_vector_type(4)));

// ---- ws layout (float offsets) ----
#define YB_OFF   0u          // 1728*2048
#define GF_OFF   3538944u
#define G_OFF    3571712u
#define E0_OFF   3604480u
#define F0_OFF   3637248u
#define EE_OFF   3670016u
#define XN_OFF   3702784u    // 884736
#define RE1_OFF  4587520u    // 512
#define PAC_OFF  4588032u    // 768
#define ST_OFF   4588800u    // 256
#define XB_OFF   4589056u    // bf16 X
#define WB_OFF   5031424u    // bf16 A1,B1,V1,U1
#define AVB_OFF  5555712u    // bf16 av (straight)
#define EPB_OFF  5686784u    // bf16 ep (straight)
#define E1B_OFF  5817856u    // bf16 E1 (straight)
#define FVT_OFF  5948928u    // bf16 fv^T
#define EPT_OFF  6080000u    // bf16 ep^T
#define T1T_OFF  6211072u    // bf16 (av@fv)^T
#define WEB_OFF  6342144u    // bf16 E1@ep
#define WC_OFF   6473216u    // fp32 ep@av@fv
#define WD_OFF   6735360u    // fp32 E1@ep@av@fv
#define BC0_OFF  6997504u
#define BC_OFF   6998016u
#define BCE_OFF  6998528u
// ST: [0..27) Sa, [27..54) Sa2, [54..81) Sc, [81..108) Sc2,
//     [108..135) sae(at), [135..162) sce(at), [162..164) se,se2(at),
//     [164..166) s_acc(at), [166..220) pbn_acc(at)

__device__ __forceinline__ unsigned short f2bf(float f) {
    unsigned int u = __float_as_uint(f);
    return (unsigned short)((u + 0x7FFFu + ((u >> 16) & 1u)) >> 16);
}

__device__ __forceinline__ float wred64(float v) {
#pragma unroll
    for (int o = 32; o; o >>= 1) v += __shfl_down(v, o, 64);
    return v;
}

// ============ job: coalesced matvec / rowsum, 64 outputs per block ============
__device__ void mv_cw(const float* __restrict__ W, const float* __restrict__ vin,
                      const float* __restrict__ badd, float* __restrict__ vout,
                      int jb, int t, char* sbuf) {
    float* vs = (float*)sbuf;
    if (t < 128) {
        float4 one = make_float4(1.f, 1.f, 1.f, 1.f);
        ((float4*)vs)[t] = vin ? ((const float4*)vin)[t] : one;
    }
    __syncthreads();
    int w = t >> 6, lane = t & 63;
    for (int o = 0; o < 16; o++) {
        int d = jb * 64 + w * 16 + o;
        const float* row = W + (size_t)d * 512;
        float4 v1 = *(const float4*)(row + lane * 4);
        float4 v2 = *(const float4*)(row + 256 + lane * 4);
        const float* va = vs + lane * 4;
        const float* vb = vs + 256 + lane * 4;
        float p = v1.x * va[0] + v1.y * va[1] + v1.z * va[2] + v1.w * va[3]
                + v2.x * vb[0] + v2.y * vb[1] + v2.z * vb[2] + v2.w * vb[3];
        p = wred64(p);
        if (lane == 0) vout[d] = p + (badd ? badd[d] : 0.f);
    }
}

// ============ dpre: gf + rE1 + zero + all bf16 conversions + bc0 ============
__global__ __launch_bounds__(256) void dpre_k(const float* __restrict__ x,
        const float* __restrict__ E1, const float* __restrict__ A1,
        const float* __restrict__ B1, const float* __restrict__ V1,
        const float* __restrict__ U1, const float* __restrict__ fv_w,
        const float* __restrict__ av_w, const float* __restrict__ ep_w,
        const float* __restrict__ fv_b, const float* __restrict__ av_b,
        float* __restrict__ ws) {
    __shared__ __align__(16) char sbuf[17408];
    int blk = blockIdx.x, t = threadIdx.x;
    if (blk < 16) {
        float* gf = ws + GF_OFF;
        for (int p = 0; p < 8; p++) {
            int q = blk * 2048 + p * 256 + t;
            int b = q >> 9, d = q & 511;
            const float* pp = x + (size_t)b * 13824 + d;
            float s = 0.f;
#pragma unroll
            for (int n = 0; n < 27; n++) s += pp[n << 9];
            gf[q] = s * (1.0f / 27.0f);
        }
    } else if (blk < 24) {
        mv_cw(E1, nullptr, nullptr, ws + RE1_OFF, blk - 16, t, sbuf);
    } else if (blk < 25) {
        float* pac = ws + PAC_OFF;
        float* ST = ws + ST_OFF;
        for (int q = t; q < 729; q += 256) pac[q] = 0.f;
        if (t < 112) ST[108 + t] = 0.f;
    } else if (blk < 52) {
        int jb = blk - 25;   // X -> bf16
        unsigned short* xb = (unsigned short*)(ws + XB_OFF);
        size_t base = (size_t)jb * 32768;
#pragma unroll
        for (int it = 0; it < 16; it++) {
            size_t e8 = base + it * 2048 + t * 8;
            float4 a = *(const float4*)(x + e8);
            float4 b = *(const float4*)(x + e8 + 4);
            uint4 pk;
            pk.x = f2bf(a.x) | ((unsigned)f2bf(a.y) << 16);
            pk.y = f2bf(a.z) | ((unsigned)f2bf(a.w) << 16);
            pk.z = f2bf(b.x) | ((unsigned)f2bf(b.y) << 16);
            pk.w = f2bf(b.z) | ((unsigned)f2bf(b.w) << 16);
            *(uint4*)(xb + e8) = pk;
        }
    } else if (blk < 84) {
        int jb = blk - 52;   // A1/B1/V1/U1 -> bf16
        const float* Wl[4] = {A1, B1, V1, U1};
        const float* src = Wl[jb >> 3] + (size_t)(jb & 7) * 32768;
        unsigned short* wb = (unsigned short*)(ws + WB_OFF) + (size_t)jb * 32768;
#pragma unroll
        for (int it = 0; it < 16; it++) {
            size_t e8 = (size_t)it * 2048 + t * 8;
            float4 a = *(const float4*)(src + e8);
            float4 b = *(const float4*)(src + e8 + 4);
            uint4 pk;
            pk.x = f2bf(a.x) | ((unsigned)f2bf(a.y) << 16);
            pk.y = f2bf(a.z) | ((unsigned)f2bf(a.w) << 16);
            pk.z = f2bf(b.x) | ((unsigned)f2bf(b.y) << 16);
            pk.w = f2bf(b.z) | ((unsigned)f2bf(b.w) << 16);
            *(uint4*)(wb + e8) = pk;
        }
    } else if (blk < 92) {
        mv_cw(av_w, fv_b, av_b, ws + BC0_OFF, blk - 84, t, sbuf);  // bc0
    } else if (blk < 116) {
        int jb = blk - 92;   // straight bf16: av, ep, E1 (8 blocks each)
        const float* Sl[3] = {av_w, ep_w, E1};
        unsigned dofs[3] = {AVB_OFF, EPB_OFF, E1B_OFF};
        const float* src = Sl[jb >> 3] + (size_t)(jb & 7) * 32768;
        unsigned short* wb = (unsigned short*)(ws + dofs[jb >> 3]) + (size_t)(jb & 7) * 32768;
#pragma unroll
        for (int it = 0; it < 16; it++) {
            size_t e8 = (size_t)it * 2048 + t * 8;
            float4 a = *(const float4*)(src + e8);
            float4 b = *(const float4*)(src + e8 + 4);
            uint4 pk;
            pk.x = f2bf(a.x) | ((unsigned)f2bf(a.y) << 16);
            pk.y = f2bf(a.z) | ((unsigned)f2bf(a.w) << 16);
            pk.z = f2bf(b.x) | ((unsigned)f2bf(b.y) << 16);
            pk.w = f2bf(b.z) | ((unsigned)f2bf(b.w) << 16);
            *(uint4*)(wb + e8) = pk;
        }
    } else {
        // transposed bf16 conv: fv^T (blk 116..179), ep^T (180..243)
        int jb = blk - 116;
        const float* src = (jb < 64) ? fv_w : ep_w;
        unsigned short* dst = (unsigned short*)(ws + ((jb < 64) ? FVT_OFF : EPT_OFF));
        int tile = jb & 63;
        int tr = (tile >> 3) * 64, tc = (tile & 7) * 64;  // src rows (k), cols (j)
        float* T = (float*)sbuf;                          // [64][67]
        {
            int row = t >> 2, cs = t & 3;
#pragma unroll
            for (int q = 0; q < 4; q++) {
                int col = cs * 16 + q * 4;
                float4 v = *(const float4*)(src + (size_t)(tr + row) * 512 + tc + col);
                T[row * 67 + col] = v.x; T[row * 67 + col + 1] = v.y;
                T[row * 67 + col + 2] = v.z; T[row * 67 + col + 3] = v.w;
            }
        }
        __syncthreads();
        {
            int jrow = t >> 2, seg = t & 3;
            unsigned u[8];
#pragma unroll
            for (int q = 0; q < 8; q++) {
                float lo = T[(seg * 16 + 2 * q) * 67 + jrow];
                float hi = T[(seg * 16 + 2 * q + 1) * 67 + jrow];
                u[q] = f2bf(lo) | ((unsigned)f2bf(hi) << 16);
            }
            unsigned short* op = dst + (size_t)(tc + jrow) * 512 + tr + seg * 16;
            *(uint4*)op = make_uint4(u[0], u[1], u[2], u[3]);
            *(uint4*)(op + 8) = make_uint4(u[4], u[5], u[6], u[7]);
        }
    }
}

// ============ M1: unified MFMA dispatch (BK=32, proven) — Yb (448) + w1 (64) ============
__global__ __launch_bounds__(256) void m1_k(const unsigned short* __restrict__ Xb,
        const unsigned short* __restrict__ Wb,
        const unsigned short* __restrict__ fvT, const unsigned short* __restrict__ avB,
        const unsigned short* __restrict__ e1B, const unsigned short* __restrict__ epT,
        float* __restrict__ Y, unsigned short* __restrict__ T1t,
        unsigned short* __restrict__ WeB) {
    __shared__ __align__(16) unsigned short As[128 * 32];
    __shared__ __align__(16) unsigned short Bs[64 * 32];
    int blk = blockIdx.x, t = threadIdx.x;
    const unsigned short* abase;
    const unsigned short* bbase;
    int rb0, mrows, col0;
    size_t ostride;
    float* outf = nullptr;
    unsigned short* outh = nullptr;
    if (blk < 448) {
        int bx = blk % 14, by = blk / 14;
        rb0 = bx * 128; mrows = 1728;
        abase = Xb;
        bbase = Wb + ((size_t)(by >> 3) * 512 + (size_t)(by & 7) * 64) * 512;
        outf = Y; col0 = by * 64; ostride = 2048;
    } else {
        int j = blk - 448;          // 0..63
        int sel = j >> 5, loc = j & 31;
        int bx = loc & 3, by = loc >> 2;
        rb0 = bx * 128; mrows = 512;
        abase = sel ? e1B : fvT;
        bbase = (sel ? epT : avB) + (size_t)(by * 64) * 512;
        outh = sel ? WeB : T1t; col0 = by * 64; ostride = 512;
    }
    bool isA = t < 128, isB = (t >= 128 && t < 192);
    int sr;
    if (isA) sr = (t & 64) + (((t & 1) << 5) | ((t & 63) >> 1));
    else { int u = (t - 128) & 63; sr = ((u & 1) << 5) | (u >> 1); }
    const unsigned short* src = nullptr;
    bool valid = false;
    if (isA) { int gr = rb0 + sr; valid = gr < mrows; src = abase + (size_t)gr * 512; }
    else if (isB) { valid = true; src = bbase + (size_t)sr * 512; }
    unsigned short* dst = (isA ? As : Bs) + sr * 32;
    int rsh = (sr >> 1) & 3;
    int wave = t >> 6, l = t & 63;
    int wr = (wave >> 1) * 64, wc = (wave & 1) * 32;
    int lr = l & 15, g = l >> 4;
    f32x4 acc[4][2] = {};
    uint4 v[4];
    uint4 z4 = make_uint4(0u, 0u, 0u, 0u);
    if (isA || isB) {
        const uint4* sp = (const uint4*)src;
#pragma unroll
        for (int i = 0; i < 4; i++) v[i] = valid ? sp[i] : z4;
    }
    for (int step = 0; step < 16; step++) {
        __syncthreads();
        if (isA || isB) {
#pragma unroll
            for (int s = 0; s < 4; s++)
                *(uint4*)(dst + (((s + rsh) & 3) << 3)) = v[s];
            if (step < 15) {
                const uint4* sp = (const uint4*)(src + (step + 1) * 32);
#pragma unroll
                for (int i = 0; i < 4; i++) v[i] = valid ? sp[i] : z4;
            }
        }
        __syncthreads();
        short8 af[4], bf[2];
#pragma unroll
        for (int m = 0; m < 4; m++) {
            int r = wr + m * 16 + lr;
            af[m] = *(const short8*)(As + r * 32 + (((g + (r >> 1)) & 3) << 3));
        }
#pragma unroll
        for (int n = 0; n < 2; n++) {
            int r = wc + n * 16 + lr;
            bf[n] = *(const short8*)(Bs + r * 32 + (((g + (r >> 1)) & 3) << 3));
        }
#pragma unroll
        for (int m = 0; m < 4; m++)
#pragma unroll
            for (int n = 0; n < 2; n++)
                acc[m][n] = __builtin_amdgcn_mfma_f32_16x16x32_bf16(af[m], bf[n], acc[m][n], 0, 0, 0);
    }
#pragma unroll
    for (int m = 0; m < 4; m++) {
        int row0 = rb0 + wr + m * 16 + g * 4;
#pragma unroll
        for (int reg = 0; reg < 4; reg++) {
            int row = row0 + reg;
            if (row < mrows) {
#pragma unroll
                for (int n = 0; n < 2; n++) {
                    int col = col0 + wc + n * 16 + lr;
                    if (outf) outf[(size_t)row * ostride + col] = acc[m][n][reg];
                    else      outh[(size_t)row * ostride + col] = f2bf(acc[m][n][reg]);
                }
            }
        }
    }
}

// ============ MFMA core for w2 jobs (proven BK=32 structure), M=512 ============
__device__ __forceinline__ void wgemm_core(const unsigned short* __restrict__ A,
        const unsigned short* __restrict__ B, float* __restrict__ Out,
        int bx, int by, int t, unsigned short* As, unsigned short* Bs) {
    int rb0 = bx * 128, n0 = by * 64;
    bool isA = t < 128, isB = (t >= 128 && t < 192);
    int sr;
    if (isA) sr = (t & 64) + (((t & 1) << 5) | ((t & 63) >> 1));
    else { int u = (t - 128) & 63; sr = ((u & 1) << 5) | (u >> 1); }
    const unsigned short* src = isA ? A + (size_t)(rb0 + sr) * 512
                                    : B + (size_t)(n0 + sr) * 512;
    unsigned short* dst = (isA ? As : Bs) + sr * 32;
    int rsh = (sr >> 1) & 3;
    int wave = t >> 6, l = t & 63;
    int wr = (wave >> 1) * 64, wc = (wave & 1) * 32;
    int lr = l & 15, g = l >> 4;
    f32x4 acc[4][2] = {};
    uint4 v[4];
    if (isA || isB) {
        const uint4* sp = (const uint4*)src;
#pragma unroll
        for (int i = 0; i < 4; i++) v[i] = sp[i];
    }
    for (int step = 0; step < 16; step++) {
        __syncthreads();
        if (isA || isB) {
#pragma unroll
            for (int s = 0; s < 4; s++)
                *(uint4*)(dst + (((s + rsh) & 3) << 3)) = v[s];
            if (step < 15) {
                const uint4* sp = (const uint4*)(src + (step + 1) * 32);
#pragma unroll
                for (int i = 0; i < 4; i++) v[i] = sp[i];
            }
        }
        __syncthreads();
        short8 af[4], bf[2];
#pragma unroll
        for (int m = 0; m < 4; m++) {
            int r = wr + m * 16 + lr;
            af[m] = *(const short8*)(As + r * 32 + (((g + (r >> 1)) & 3) << 3));
        }
#pragma unroll
        for (int n = 0; n < 2; n++) {
            int r = wc + n * 16 + lr;
            bf[n] = *(const short8*)(Bs + r * 32 + (((g + (r >> 1)) & 3) << 3));
        }
#pragma unroll
        for (int m = 0; m < 4; m++)
#pragma unroll
            for (int n = 0; n < 2; n++)
                acc[m][n] = __builtin_amdgcn_mfma_f32_16x16x32_bf16(af[m], bf[n], acc[m][n], 0, 0, 0);
    }
#pragma unroll
    for (int m = 0; m < 4; m++) {
        int row0 = rb0 + wr + m * 16 + g * 4;
#pragma unroll
        for (int reg = 0; reg < 4; reg++) {
            int row = row0 + reg;
#pragma unroll
            for (int n = 0; n < 2; n++)
                Out[(size_t)row * 512 + n0 + wc + n * 16 + lr] = acc[m][n][reg];
        }
    }
}

// ============ job: Out[64x512]=A@W^T, 4 d/block; As[64][132] direct layout ============
__device__ void dense4x_job(const float* __restrict__ A, const float* __restrict__ W,
                            const float* __restrict__ bias, float* __restrict__ Out,
                            int jb, int t, char* sbuf, int mode, float* __restrict__ ST) {
    float* As = (float*)sbuf;          // [64][132]
    float* Ws = As + 64 * 132;         // [4][132]
    float* red = Ws + 4 * 132;         // [8]
    int d0 = jb * 4;
    int b = t & 63, dg = t >> 6;
    int d = d0 + dg;
    float a0 = 0.f, a1 = 0.f, a2 = 0.f, a3 = 0.f;
    for (int c = 0; c < 4; c++) {
        int k0 = c * 128;
#pragma unroll
        for (int r = 0; r < 8; r++) {
            int p = t + r * 256;
            int row = p >> 5, c4 = p & 31;
            *(float4*)(As + row * 132 + c4 * 4) =
                *(const float4*)(A + (size_t)row * 512 + k0 + c4 * 4);
        }
        if (t < 128) {
            int drow = t >> 5, c4 = t & 31;
            *(float4*)(Ws + drow * 132 + c4 * 4) =
                *(const float4*)(W + (size_t)(d0 + drow) * 512 + k0 + c4 * 4);
        }
        __syncthreads();
        const float4* ap = (const float4*)(As + b * 132);
        const float4* wp = (const float4*)(Ws + dg * 132);
#pragma unroll 8
        for (int kq = 0; kq < 32; kq += 4) {
            float4 x0 = ap[kq], w0 = wp[kq];
            float4 x1 = ap[kq + 1], w1 = wp[kq + 1];
            float4 x2 = ap[kq + 2], w2 = wp[kq + 2];
            float4 x3 = ap[kq + 3], w3 = wp[kq + 3];
            a0 = fmaf(x0.x, w0.x, fmaf(x0.y, w0.y, fmaf(x0.z, w0.z, fmaf(x0.w, w0.w, a0))));
            a1 = fmaf(x1.x, w1.x, fmaf(x1.y, w1.y, fmaf(x1.z, w1.z, fmaf(x1.w, w1.w, a1))));
            a2 = fmaf(x2.x, w2.x, fmaf(x2.y, w2.y, fmaf(x2.z, w2.z, fmaf(x2.w, w2.w, a2))));
            a3 = fmaf(x3.x, w3.x, fmaf(x3.y, w3.y, fmaf(x3.z, w3.z, fmaf(x3.w, w3.w, a3))));
        }
        __syncthreads();
    }
    float val = (a0 + a1) + (a2 + a3) + (bias ? bias[d] : 0.f);
    if (mode == 1) {
        float sv = __shfl(wred64(val), 0, 64);
        float sv2 = __shfl(wred64(val * val), 0, 64);
        float mm = sv * (1.f / 64.f);
        float var = sv2 * (1.f / 64.f) - mm * mm;
        val = fmaxf((val - mm) / sqrtf(var + EPSC), 0.f);
    }
    Out[b * 512 + d] = val;
    if (mode == 2) {
        float s = wred64(val), s2 = wred64(val * val);
        if ((t & 63) == 0) { red[dg * 2] = s; red[dg * 2 + 1] = s2; }
        __syncthreads();
        if (t == 0) {
            atomicAdd(ST + 164, red[0] + red[2] + red[4] + red[6]);
            atomicAdd(ST + 165, red[1] + red[3] + red[5] + red[7]);
        }
    }
}

// ============ job: Gram partials (atomic) ============
__device__ void gram_job(const float* __restrict__ Yb, float* __restrict__ pac,
                         int b, int t, char* sbuf) {
    float* As = (float*)sbuf;        // [27][132]
    float* Cs = As + 27 * 132;
    float a0 = 0, a1 = 0, a2 = 0;
    int i = t / 9, j0 = (t % 9) * 3;
    for (int dc = 0; dc < 4; dc++) {
        const float* base = Yb + (size_t)b * 27 * 2048 + dc * 128;
#pragma unroll
        for (int r = 0; r < 4; r++) {
            int id = t + r * 256;
            if (id < 864) {
                int row = id >> 5, c4 = (id & 31) << 2;
                *(float4*)&As[row * 132 + c4] = *(const float4*)(base + (size_t)row * 2048 + c4);
                *(float4*)&Cs[row * 132 + c4] = *(const float4*)(base + (size_t)row * 2048 + 512 + c4);
            }
        }
        __syncthreads();
        if (t < 243) {
#pragma unroll
            for (int k = 0; k < 128; k += 4) {
                float4 av = *(const float4*)&As[i * 132 + k];
                float4 c0 = *(const float4*)&Cs[j0 * 132 + k];
                float4 c1 = *(const float4*)&Cs[(j0 + 1) * 132 + k];
                float4 c2 = *(const float4*)&Cs[(j0 + 2) * 132 + k];
                a0 += av.x * c0.x + av.y * c0.y + av.z * c0.z + av.w * c0.w;
                a1 += av.x * c1.x + av.y * c1.y + av.z * c1.z + av.w * c1.w;
                a2 += av.x * c2.x + av.y * c2.y + av.z * c2.z + av.w * c2.w;
            }
        }
        __syncthreads();
    }
    if (t < 243) {
        atomicAdd(pac + i * 27 + j0, a0);
        atomicAdd(pac + i * 27 + j0 + 1, a1);
        atomicAdd(pac + i * 27 + j0 + 2, a2);
    }
}

// ============ job: per-i a/c sums — float4 + unroll ============
__device__ void acsum_job(const float* __restrict__ Yb, float* __restrict__ ST,
                          int ia, int t, char* sbuf) {
    int i = ia < 27 ? ia : ia - 27;
    int off = ia < 27 ? 0 : 512;
    float s = 0, s2 = 0;
#pragma unroll 8
    for (int q4 = t; q4 < 8192; q4 += 256) {
        int b = q4 >> 7, d4 = (q4 & 127) << 2;
        float4 v = *(const float4*)(Yb + (size_t)(b * 27 + i) * 2048 + off + d4);
        s += (v.x + v.y) + (v.z + v.w);
        s2 += v.x * v.x + v.y * v.y + v.z * v.z + v.w * v.w;
    }
    s = wred64(s); s2 = wred64(s2);
    float* p = (float*)sbuf;
    int wv_ = t >> 6;
    if ((t & 63) == 0) { p[wv_ * 2] = s; p[wv_ * 2 + 1] = s2; }
    __syncthreads();
    if (t == 0) {
        float S = p[0] + p[2] + p[4] + p[6];
        float S2 = p[1] + p[3] + p[5] + p[7];
        if (ia < 27) { ST[ia] = S; ST[27 + ia] = S2; }
        else { ST[54 + (ia - 27)] = S; ST[81 + (ia - 27)] = S2; }
    }
}

// ============ D2: w2 (64) + g (128) + gram (64) + acsum (54) + bc (8) ============
__global__ __launch_bounds__(256) void d2_k(const float* __restrict__ gl_w,
        const float* __restrict__ gl_b, const float* __restrict__ ep_w,
        const float* __restrict__ ep_b, float* __restrict__ ws) {
    __shared__ __align__(16) char sbuf[36032];
    int blk = blockIdx.x, t = threadIdx.x;
    if (blk < 64) {
        unsigned short* As = (unsigned short*)sbuf;
        unsigned short* Bs = As + 128 * 32;
        int sel = blk >> 5, loc = blk & 31;
        const unsigned short* epB = (const unsigned short*)(ws + EPB_OFF);
        const unsigned short* WeB = (const unsigned short*)(ws + WEB_OFF);
        const unsigned short* T1t = (const unsigned short*)(ws + T1T_OFF);
        wgemm_core(sel ? WeB : epB, T1t, sel ? (ws + WD_OFF) : (ws + WC_OFF),
                   loc & 3, loc >> 2, t, As, Bs);
    } else if (blk < 192) {
        dense4x_job(ws + GF_OFF, gl_w, gl_b, ws + G_OFF, blk - 64, t, sbuf, 1, nullptr);
    } else if (blk < 256) {
        gram_job(ws + YB_OFF, ws + PAC_OFF, blk - 192, t, sbuf);
    } else if (blk < 310) {
        acsum_job(ws + YB_OFF, ws + ST_OFF, blk - 256, t, sbuf);
    } else {
        mv_cw(ep_w, ws + BC0_OFF, ep_b, ws + BC_OFF, blk - 310, t, sbuf);
    }
}

// ============ D3: e0 = g@Wc^T+bc (stats) + f0 = g@Wd^T + bcE matvec ============
__global__ __launch_bounds__(256) void d3_k(const float* __restrict__ E1,
        float* __restrict__ ws) {
    __shared__ __align__(16) char sbuf[36032];
    int blk = blockIdx.x, t = threadIdx.x;
    if (blk < 128) {
        dense4x_job(ws + G_OFF, ws + WC_OFF, ws + BC_OFF, ws + E0_OFF,
                    blk, t, sbuf, 2, ws + ST_OFF);
    } else if (blk < 256) {
        dense4x_job(ws + G_OFF, ws + WD_OFF, nullptr, ws + F0_OFF,
                    blk - 128, t, sbuf, 0, nullptr);
    } else {
        mv_cw(E1, ws + BC_OFF, nullptr, ws + BCE_OFF, blk - 256, t, sbuf);
    }
}

// ============ D4: eE + se/se2 (8) + sae/sce (216) — float4 ============
__global__ __launch_bounds__(256) void d4_k(float* __restrict__ ws) {
    __shared__ __align__(16) char sbuf[64];
    int blk = blockIdx.x, t = threadIdx.x;
    const float* Yb = ws + YB_OFF;
    const float* f0 = ws + F0_OFF;
    const float* bcE = ws + BCE_OFF;
    const float* rE1 = ws + RE1_OFF;
    float* ST = ws + ST_OFF;
    float m = ST[164] * (1.f / 32768.f);
    float var = ST[165] * (1.f / 32768.f) - m * m;
    float rs = 1.f / sqrtf(var + EPSC);
    float* p = (float*)sbuf;
    int wv_ = t >> 6;
    if (blk < 8) {
        float se = 0.f, se2 = 0.f;
#pragma unroll
        for (int r = 0; r < 4; r++) {
            int q4 = blk * 1024 + r * 256 + t;
            int d4 = (q4 & 127) << 2;
            float4 f = *(const float4*)(f0 + q4 * 4);
            float4 bc4 = *(const float4*)(bcE + d4);
            float4 re4 = *(const float4*)(rE1 + d4);
            float4 e;
            e.x = rs * (f.x + bc4.x - m * re4.x);
            e.y = rs * (f.y + bc4.y - m * re4.y);
            e.z = rs * (f.z + bc4.z - m * re4.z);
            e.w = rs * (f.w + bc4.w - m * re4.w);
            *(float4*)(ws + EE_OFF + q4 * 4) = e;
            se += (e.x + e.y) + (e.z + e.w);
            se2 += e.x * e.x + e.y * e.y + e.z * e.z + e.w * e.w;
        }
        se = wred64(se); se2 = wred64(se2);
        if ((t & 63) == 0) { p[wv_ * 2] = se; p[wv_ * 2 + 1] = se2; }
        __syncthreads();
        if (t == 0) {
            atomicAdd(ST + 162, p[0] + p[2] + p[4] + p[6]);
            atomicAdd(ST + 163, p[1] + p[3] + p[5] + p[7]);
        }
    } else {
        int blk2 = blk - 8;
        int i = blk2 % 27, bg = blk2 / 27;
        float sae = 0.f, sce = 0.f;
#pragma unroll
        for (int r = 0; r < 4; r++) {
            int q4 = r * 256 + t;               // 0..1023 over 8 b x 128 f4
            int bb = bg * 8 + (q4 >> 7);
            int d4 = (q4 & 127) << 2;
            float4 f = *(const float4*)(f0 + bb * 512 + d4);
            float4 bc4 = *(const float4*)(bcE + d4);
            float4 re4 = *(const float4*)(rE1 + d4);
            float4 e;
            e.x = rs * (f.x + bc4.x - m * re4.x);
            e.y = rs * (f.y + bc4.y - m * re4.y);
            e.z = rs * (f.z + bc4.z - m * re4.z);
            e.w = rs * (f.w + bc4.w - m * re4.w);
            size_t base = (size_t)(bb * 27 + i) * 2048 + d4;
            float4 av = *(const float4*)(Yb + base);
            float4 cv = *(const float4*)(Yb + base + 512);
            sae += av.x * e.x + av.y * e.y + av.z * e.z + av.w * e.w;
            sce += cv.x * e.x + cv.y * e.y + cv.z * e.z + cv.w * e.w;
        }
        sae = wred64(sae); sce = wred64(sce);
        if ((t & 63) == 0) { p[wv_ * 2] = sae; p[wv_ * 2 + 1] = sce; }
        __syncthreads();
        if (t == 0) {
            atomicAdd(ST + 108 + i, p[0] + p[2] + p[4] + p[6]);
            atomicAdd(ST + 135 + i, p[1] + p[3] + p[5] + p[7]);
        }
    }
}

// ============ D8: fuse gate/softmax/aggregate (512 blocks, i-split) ============
__global__ __launch_bounds__(256) void d8_k(float* __restrict__ ws) {
    __shared__ __align__(16) char sbuf[5888];
    int blk = blockIdx.x, t = threadIdx.x;
    const float* Yb = ws + YB_OFF;
    const float* eE = ws + EE_OFF;
    const float* e0 = ws + E0_OFF;
    const float* pac = ws + PAC_OFF;
    float* ST = ws + ST_OFF;
    float* xn = ws + XN_OFF;
    float* pbn_acc = ST + 166;
    float* rstL = (float*)sbuf;      // 736
    float* pmsL = rstL + 736;
    int b = blk >> 3, r3 = blk & 7;
    int ds4 = (r3 >> 1) * 128, ih = r3 & 1;
    int i0 = ih ? 14 : 0, i1 = ih ? 27 : 14;
    float Se = ST[162], Se2 = ST[163];
    const float inv = 1.f / 32768.f;
    float mE = ST[164] * inv;
    float varE = ST[165] * inv - mE * mE;
    float rsE = 1.f / sqrtf(varE + EPSC);
    for (int id = i0 * 27 + t; id < i1 * 27; id += 256) {
        int i = id / 27, j = id - i * 27;
        float m = (ST[i] + ST[54 + j] + Se) * inv;
        float S2 = ST[27 + i] + ST[81 + j] + Se2 + 2.f * (pac[id] + ST[108 + i] + ST[135 + j]);
        float var = S2 * inv - m * m;
        float rst = 1.f / sqrtf(var + EPSC);
        rstL[id] = rst; pmsL[id] = -m * rst;
    }
    __syncthreads();
    int j = t & 127, sub = t >> 7;
    float ev = eE[b * 512 + ds4 + j];
    float env = (e0[b * 512 + ds4 + j] - mE) * rsE;
    float cr[27], ur[27];
#pragma unroll
    for (int jj = 0; jj < 27; ++jj) {
        size_t rb = (size_t)(b * 27 + jj) * 2048 + ds4 + j;
        cr[jj] = Yb[rb + 512];
        ur[jj] = Yb[rb + 1024];
    }
    const float L2E = 1.4426950408889634f;
    for (int i = i0 + sub; i < i1; i += 2) {
        size_t rb = (size_t)(b * 27 + i) * 2048 + ds4 + j;
        float t1 = Yb[rb] + ev;
        const float* prst = rstL + i * 27;
        const float* ppms = pmsL + i * 27;
        float num = 0.f, den = 0.f;
#pragma unroll
        for (int jj = 0; jj < 27; ++jj) {
            float bn = fmaf(t1 + cr[jj], prst[jj], ppms[jj]);
            float r = fmaxf(bn, 0.f);
            float z = env + r;
            float tt = __builtin_amdgcn_exp2f(z * -L2E);
            float sg = __builtin_amdgcn_rcpf(1.f + tt);
            float w2 = __builtin_amdgcn_exp2f(sg * L2E);
            den += w2;
            num = fmaf(w2, ur[jj], num);
        }
        xn[(size_t)b * 13824 + i * 512 + ds4 + j] =
            Yb[rb + 1536] + num * __builtin_amdgcn_rcpf(den) * (1.f / 27.f);
    }
    __syncthreads();
    if (t >= i0 && t < i1) {
        float s = 0, s2 = 0;
        const float4* xp = (const float4*)(xn + (size_t)b * 13824 + t * 512 + ds4);
#pragma unroll 8
        for (int q = 0; q < 32; q++) {
            float4 v = xp[q];
            s += (v.x + v.y) + (v.z + v.w);
            s2 += v.x * v.x + v.y * v.y + v.z * v.z + v.w * v.w;
        }
        atomicAdd(pbn_acc + t * 2, s);
        atomicAdd(pbn_acc + t * 2 + 1, s2);
    }
}

// ============ D9: per-n BN + residual relu ============
__global__ __launch_bounds__(256) void d9_k(const float* __restrict__ x,
        float* __restrict__ ws, float* __restrict__ out) {
    __shared__ __align__(16) char sbuf[256];
    int blk = blockIdx.x, t = threadIdx.x;
    const float* xn = ws + XN_OFF;
    const float* pbn_acc = ws + ST_OFF + 166;
    float* m2L = (float*)sbuf;
    float* rs2L = m2L + 32;
    if (t < 27) {
        float S = pbn_acc[t * 2], S2 = pbn_acc[t * 2 + 1];
        float m = S * (1.f / 32768.f);
        float var = S2 * (1.f / 32768.f) - m * m;
        m2L[t] = m; rs2L[t] = 1.f / sqrtf(var + EPSC);
    }
    __syncthreads();
    int b = blk >> 2, ds4 = (blk & 3) * 128;
    int j = t & 127, nh = t >> 7;
    int n0 = nh * 14, n1 = nh ? 27 : 14;
#pragma unroll 4
    for (int n = n0; n < n1; ++n) {
        size_t xi = (size_t)b * 13824 + n * 512 + ds4 + j;
        out[xi] = fmaxf(fmaf(xn[xi] - m2L[n], rs2L[n], x[xi]), 0.f);
    }
}

extern "C" void kernel_launch(void* const* d_in, const int* in_sizes, int n_in,
                              void* d_out, int out_size, void* d_ws, size_t ws_size,
                              hipStream_t stream) {
    const float* x    = (const float*)d_in[0];
    const float* gl_w = (const float*)d_in[1];
    const float* gl_b = (const float*)d_in[2];
    const float* fv_w = (const float*)d_in[7];
    const float* fv_b = (const float*)d_in[8];
    const float* av_w = (const float*)d_in[13];
    const float* av_b = (const float*)d_in[14];
    const float* ep_w = (const float*)d_in[15];
    const float* ep_b = (const float*)d_in[16];
    const float* U1   = (const float*)d_in[17];
    const float* V1   = (const float*)d_in[18];
    const float* A1   = (const float*)d_in[19];
    const float* B1   = (const float*)d_in[20];
    const float* E1   = (const float*)d_in[21];
    float* out = (float*)d_out;
    float* ws = (float*)d_ws;

    dpre_k<<<244, 256, 0, stream>>>(x, E1, A1, B1, V1, U1, fv_w, av_w, ep_w,
                                    fv_b, av_b, ws);
    m1_k<<<512, 256, 0, stream>>>((const unsigned short*)(ws + XB_OFF),
                                  (const unsigned short*)(ws + WB_OFF),
                                  (const unsigned short*)(ws + FVT_OFF),
                                  (const unsigned short*)(ws + AVB_OFF),
                                  (const unsigned short*)(ws + E1B_OFF),
                                  (const unsigned short*)(ws + EPT_OFF),
                                  ws + YB_OFF,
                                  (unsigned short*)(ws + T1T_OFF),
                                  (unsigned short*)(ws + WEB_OFF));
    d2_k<<<318, 256, 0, stream>>>(gl_w, gl_b, ep_w, ep_b, ws);
    d3_k<<<264, 256, 0, stream>>>(E1, ws);
    d4_k<<<224, 256, 0, stream>>>(ws);
    d8_k<<<512, 256, 0, stream>>>(ws);
    d9_k<<<256, 256, 0, stream>>>(x, ws, out);
}